// Round 11
// baseline (100.209 us; speedup 1.0000x reference)
//
#include <hip/hip_runtime.h>

#define D        128
#define KCODES   2048
#define NROWS    32768
#define BATCH    8192

typedef _Float16 f16x8 __attribute__((ext_vector_type(8)));
typedef float    f32x4 __attribute__((ext_vector_type(4)));

#define MFMA16(a, b, c) __builtin_amdgcn_mfma_f32_16x16x32_f16((a), (b), (c), 0, 0, 0)
#define INV2048 4.8828125e-4f

static __device__ __forceinline__ void gload16(const void* g, void* l) {
    __builtin_amdgcn_global_load_lds(
        (const __attribute__((address_space(1))) unsigned int*)g,
        (__attribute__((address_space(3))) unsigned int*)l, 16, 0, 0);
}

// ---------------------------------------------------------------------------
// Kernel A: W -> (wh, wl) fp16 hi/lo in 16x16x32 FRAGMENT-LINEAR layout +
// fp32 ||W||^2.  For 16-code tile n0, kstep ks (32 k's), lane l holds
// W[n0*16 + (l&15)][ks*32 + (l>>4)*8 + j], stored at f16x8 idx ((n0*4+ks)*64+l).
// (Same convention family as the R2-verified 32x32x16 layout.)
// ---------------------------------------------------------------------------
__global__ void wconv_kernel(const float* __restrict__ W,
                             _Float16* __restrict__ whf, _Float16* __restrict__ wlf,
                             float* __restrict__ wnorm) {
    int gid = blockIdx.x * 256 + threadIdx.x;    // 32768 = 2048 codes x 16 slots
    int n = gid >> 4, s = gid & 15;              // code n, 8-col slot s
    const float4* src = (const float4*)(W + (size_t)n * D + s * 8);
    float4 a = src[0], b = src[1];
    float va[8] = {a.x, a.y, a.z, a.w, b.x, b.y, b.z, b.w};
    f16x8 hi, lo;
    float ss = 0.0f;
#pragma unroll
    for (int j = 0; j < 8; ++j) {
        _Float16 h = (_Float16)va[j];
        hi[j] = h;
        lo[j] = (_Float16)((va[j] - (float)h) * 2048.0f);
        ss += va[j] * va[j];
    }
    // frag coords: n0 = n>>4, within-tile row = n&15, ks = s>>2, kgroup = s&3
    size_t idx = ((size_t)((n >> 4) * 4 + (s >> 2)) * 64 + (s & 3) * 16 + (n & 15));
    ((f16x8*)whf)[idx] = hi;
    ((f16x8*)wlf)[idx] = lo;
#pragma unroll
    for (int m = 1; m <= 8; m <<= 1) ss += __shfl_xor(ss, m);
    if (s == 0) wnorm[n] = ss;
}

// ---------------------------------------------------------------------------
// Kernel B: fused MFMA scores + argmin — 16x16x32 shape, dual-acc 16 chains.
// Grid 512 = 128 row-blocks(256 rows) x 4 code-quarters (XCD-pinned pairs).
// Block 512 thr = 8 waves x 32 rows, ALL waves share the chunk's 64 codes.
// 8 chunks of 64 codes; 2 x 32KB LDS dbuf + 2KB wnorm = 66KB -> 2 blocks/CU.
// Per chunk per wave: 32 ds_read_b128 + 96 MFMA(16x16x32); acc = 2rt x 4ct
// x {C,H} = 16 chains x f32x4 (64 regs).  A-frags hold -2*f hi/lo.
// ---------------------------------------------------------------------------
extern "C" __global__ void __launch_bounds__(512)
__attribute__((amdgpu_flat_work_group_size(512, 512)))
__attribute__((amdgpu_waves_per_eu(2, 4)))
vq_argmin(const float* __restrict__ f,
          const _Float16* __restrict__ whf, const _Float16* __restrict__ wlf,
          const float* __restrict__ wnorm,
          float* __restrict__ bsp, int* __restrict__ bcp) {
    extern __shared__ unsigned char lds[];   // [2][32768] dbuf | wnorm @65536

    const int b   = blockIdx.x;
    const int xcd = b & 7;
    const int qrt = xcd >> 1;                 // quarter 0..3 (2 XCDs each)
    const int rb  = (b >> 3) * 2 + (b & 1);   // row block 0..127 (256 rows)
    const int tid = threadIdx.x;
    const int w   = tid >> 6, l = tid & 63;
    const int l15 = l & 15, lq = l >> 4;      // frag col / k-group
    const int rowsBase = rb * 256 + w * 32;

    const char* ghB = (const char*)whf + (size_t)qrt * 131072;
    const char* glB = (const char*)wlf + (size_t)qrt * 131072;

    // chunk c: 64 codes = 16KB hi + 16KB lo
#define STAGE(c) {                                                          \
        unsigned char* dB = lds + ((c) & 1) * 32768;                        \
        gload16(ghB + (size_t)(c) * 16384 + tid * 16,        dB + tid * 16);\
        gload16(ghB + (size_t)(c) * 16384 + 8192 + tid * 16, dB + 8192 + tid * 16);\
        gload16(glB + (size_t)(c) * 16384 + tid * 16,        dB + 16384 + tid * 16);\
        gload16(glB + (size_t)(c) * 16384 + 8192 + tid * 16, dB + 24576 + tid * 16);\
    }

    if (tid < 128)
        gload16((const char*)wnorm + qrt * 2048 + tid * 16, lds + 65536 + tid * 16);
    STAGE(0);

    // ---- A-fragments: 32 rows of (-2*f), hi/lo fp16, 16x16x32 layout ----
    f16x8 fh[2][4], fl[2][4];
#pragma unroll
    for (int rt = 0; rt < 2; ++rt) {
#pragma unroll
        for (int ks = 0; ks < 4; ++ks) {
            const float4* p = (const float4*)(f + (size_t)(rowsBase + rt * 16 + l15) * D
                                              + ks * 32 + lq * 8);
            float4 a = p[0], bb = p[1];
            float va[8] = {a.x, a.y, a.z, a.w, bb.x, bb.y, bb.z, bb.w};
            f16x8 hi, lo;
#pragma unroll
            for (int j = 0; j < 8; ++j) {
                float x = -2.0f * va[j];
                _Float16 h = (_Float16)x;
                hi[j] = h;
                lo[j] = (_Float16)((x - (float)h) * 2048.0f);
            }
            fh[rt][ks] = hi;
            fl[rt][ks] = lo;
        }
    }

    __syncthreads();     // chunk 0 + wnorm staged (full vmcnt drain)

    const float* wnL = (const float*)(lds + 65536);

    float bestP[8];
#pragma unroll
    for (int e = 0; e < 8; ++e) bestP[e] = 3.4e38f;

#pragma unroll 1
    for (int t = 0; t < 8; ++t) {
        if (t > 0) {
            asm volatile("s_waitcnt vmcnt(0)" ::: "memory");
            __builtin_amdgcn_s_barrier();
            asm volatile("" ::: "memory");
        }
        if (t < 7) STAGE(t + 1);

        const unsigned char* wb = lds + (t & 1) * 32768;

        f32x4 accC[2][4], accH[2][4];
#pragma unroll
        for (int rt = 0; rt < 2; ++rt)
#pragma unroll
            for (int ct = 0; ct < 4; ++ct)
#pragma unroll
                for (int r = 0; r < 4; ++r) { accC[rt][ct][r] = 0.0f; accH[rt][ct][r] = 0.0f; }

#pragma unroll
        for (int ks = 0; ks < 4; ++ks) {
            f16x8 wh[4], wl[4];
#pragma unroll
            for (int ct = 0; ct < 4; ++ct) {
                wh[ct] = *(const f16x8*)(wb + ((ct * 4 + ks) << 10) + l * 16);
                wl[ct] = *(const f16x8*)(wb + 16384 + ((ct * 4 + ks) << 10) + l * 16);
            }
            __builtin_amdgcn_s_setprio(1);
            // 24 MFMAs, 16 chains, same-chain gap 16
#pragma unroll
            for (int ct = 0; ct < 4; ++ct) {
                accC[0][ct] = MFMA16(fh[0][ks], wl[ct], accC[0][ct]);
                accC[1][ct] = MFMA16(fh[1][ks], wl[ct], accC[1][ct]);
            }
#pragma unroll
            for (int ct = 0; ct < 4; ++ct) {
                accH[0][ct] = MFMA16(fh[0][ks], wh[ct], accH[0][ct]);
                accH[1][ct] = MFMA16(fh[1][ks], wh[ct], accH[1][ct]);
            }
#pragma unroll
            for (int ct = 0; ct < 4; ++ct) {
                accC[0][ct] = MFMA16(fl[0][ks], wh[ct], accC[0][ct]);
                accC[1][ct] = MFMA16(fl[1][ks], wh[ct], accC[1][ct]);
            }
            __builtin_amdgcn_s_setprio(0);
        }

        // ---- fold: s = wv + accH + accC/2048; meta = t*4+ct in low 5 bits ----
#pragma unroll
        for (int ct = 0; ct < 4; ++ct) {
            const float wv = wnL[t * 64 + ct * 16 + l15];
            const unsigned mv = (unsigned)(t * 4 + ct);
#pragma unroll
            for (int rt = 0; rt < 2; ++rt)
#pragma unroll
                for (int r = 0; r < 4; ++r) {
                    float s = wv + fmaf(accC[rt][ct][r], INV2048, accH[rt][ct][r]);
                    unsigned p = (__float_as_uint(s) & 0xFFFFFFE0u) | mv;
                    const int e = rt * 4 + r;
                    bestP[e] = fminf(bestP[e], __uint_as_float(p));
                }
        }
    }
#undef STAGE

    // ---- butterfly over 16 code-cols (masks 1..8); write quarter partials ----
#pragma unroll
    for (int e = 0; e < 8; ++e) {
        const int rt = e >> 2, r = e & 3;
        float s = bestP[e];
        unsigned m = __float_as_uint(s) & 31u;
        int c = qrt * 512 + (int)(m >> 2) * 64 + (int)(m & 3) * 16 + l15;
#pragma unroll
        for (int msk = 1; msk <= 8; msk <<= 1) {
            float s2 = __shfl_xor(s, msk);
            int   c2 = __shfl_xor(c, msk);
            if (s2 < s || (s2 == s && c2 < c)) { s = s2; c = c2; }
        }
        if (l15 == 0) {
            int row = rowsBase + rt * 16 + lq * 4 + r;
            bsp[(size_t)qrt * NROWS + row] = s;
            bcp[(size_t)qrt * NROWS + row] = c;
        }
    }
}

// ---------------------------------------------------------------------------
// Kernel C: merge the 4 quarter partials, gather W[j], write out + loss.
// ---------------------------------------------------------------------------
__global__ void gather_kernel(const float* __restrict__ f, const float* __restrict__ W,
                              const float* __restrict__ bsp, const int* __restrict__ bcp,
                              float* __restrict__ loss, float* __restrict__ outv) {
    int b  = blockIdx.x;
    int wv = threadIdx.x >> 6;
    int l  = threadIdx.x & 63;
    int n  = b * 4 + wv;
    float s; int c;
    if (l < 4) { s = bsp[(size_t)l * NROWS + n]; c = bcp[(size_t)l * NROWS + n]; }
    else       { s = 3.4e38f; c = 0x7FFFFFFF; }
#pragma unroll
    for (int msk = 1; msk <= 2; msk <<= 1) {
        float s2 = __shfl_xor(s, msk);
        int   c2 = __shfl_xor(c, msk);
        if (s2 < s || (s2 == s && c2 < c)) { s = s2; c = c2; }
    }
    int j = __shfl(c, 0);
    float2 fv = reinterpret_cast<const float2*>(f + (size_t)n * D)[l];
    float2 wj = reinterpret_cast<const float2*>(W + (size_t)j * D)[l];
    reinterpret_cast<float2*>(outv + (size_t)n * D)[l] = wj;
    float dx = fv.x - wj.x, dy = fv.y - wj.y;
    float ls = dx * dx + dy * dy;
#pragma unroll
    for (int off = 32; off; off >>= 1) ls += __shfl_down(ls, off);
    __shared__ float lsm[4];
    if (l == 0) lsm[wv] = ls;
    __syncthreads();
    if (threadIdx.x == 0)
        loss[b] = 1.25f * 0.25f * (lsm[0] + lsm[1] + lsm[2] + lsm[3]);
}

// ---------------------------------------------------------------------------
// ABLATION: register-only MFMA, same count/chain structure as vq_argmin
// (8 t-iters x 96 MFMA per wave, 16 chains). No LDS, no barriers, no staging.
// Measures the matrix-pipe ceiling for this issue structure. Writes scratch.
// ---------------------------------------------------------------------------
extern "C" __global__ void __launch_bounds__(512)
__attribute__((amdgpu_flat_work_group_size(512, 512)))
__attribute__((amdgpu_waves_per_eu(2, 4)))
ab_puremfma(const _Float16* __restrict__ whf, float* __restrict__ outd) {
    const int b = blockIdx.x;
    const int tid = threadIdx.x;
    const int w = tid >> 6, l = tid & 63;
    // opaque operands from global (compiler can't fold)
    const f16x8* wv8 = (const f16x8*)whf;
    f16x8 A0 = wv8[l], A1 = wv8[64 + l], A2 = wv8[128 + l], A3 = wv8[192 + l];
    f16x8 B0 = wv8[256 + l], B1 = wv8[320 + l], B2 = wv8[384 + l], B3 = wv8[448 + l];

    f32x4 accC[2][4], accH[2][4];
#pragma unroll
    for (int rt = 0; rt < 2; ++rt)
#pragma unroll
        for (int ct = 0; ct < 4; ++ct)
#pragma unroll
            for (int r = 0; r < 4; ++r) { accC[rt][ct][r] = 0.0f; accH[rt][ct][r] = 0.0f; }

#pragma unroll 1
    for (int t = 0; t < 8; ++t) {
#pragma unroll
        for (int ks = 0; ks < 4; ++ks) {
#pragma unroll
            for (int ct = 0; ct < 4; ++ct) {
                f16x8 bb = (ct & 1) ? B1 : B0;
                accC[0][ct] = MFMA16(A0, bb, accC[0][ct]);
                accC[1][ct] = MFMA16(A1, bb, accC[1][ct]);
            }
#pragma unroll
            for (int ct = 0; ct < 4; ++ct) {
                f16x8 bb = (ct & 1) ? B3 : B2;
                accH[0][ct] = MFMA16(A0, bb, accH[0][ct]);
                accH[1][ct] = MFMA16(A1, bb, accH[1][ct]);
            }
#pragma unroll
            for (int ct = 0; ct < 4; ++ct) {
                f16x8 bb = (ct & 1) ? B1 : B0;
                accC[0][ct] = MFMA16(A2, bb, accC[0][ct]);
                accC[1][ct] = MFMA16(A3, bb, accC[1][ct]);
            }
        }
    }
    // keep everything live; small scratch write
    float v = 0.0f;
#pragma unroll
    for (int rt = 0; rt < 2; ++rt)
#pragma unroll
        for (int ct = 0; ct < 4; ++ct)
            v += accC[rt][ct][0] + accH[rt][ct][1];
    if (w == 0) outd[b * 64 + l] = v;
}

// ---------------------------------------------------------------------------
extern "C" void kernel_launch(void* const* d_in, const int* in_sizes, int n_in,
                              void* d_out, int out_size, void* d_ws, size_t ws_size,
                              hipStream_t stream) {
    const float* f = (const float*)d_in[0];   // [8192,512] -> 32768 rows of 128
    const float* W = (const float*)d_in[1];   // [2048,128]

    float* loss = (float*)d_out;              // [8192]
    float* outv = (float*)d_out + BATCH;      // [8192*512]

    // workspace layout
    float*    wnorm = (float*)d_ws;                              // @0       (8 KB)
    _Float16* whf   = (_Float16*)((char*)d_ws + 8192);           // @8K    (512 KB)
    _Float16* wlf   = (_Float16*)((char*)d_ws + 532480);         // @520K  (512 KB)
    float*    bsp   = (float*)((char*)d_ws + 1056768);           //        (512 KB)
    int*      bcp   = (int*)((char*)d_ws + 1581056);             //        (512 KB)

    wconv_kernel<<<KCODES * 16 / 256, 256, 0, stream>>>(W, whf, wlf, wnorm);

    hipLaunchKernelGGL(vq_argmin, dim3(512), dim3(512), 67584, stream,
                       f, whf, wlf, wnorm, bsp, bcp);

    gather_kernel<<<BATCH, 256, 0, stream>>>(f, W, bsp, bcp, loss, outv);

    // ablation dispatch (writes bsp scratch only; after gather consumed it)
    ab_puremfma<<<512, 512, 0, stream>>>(whf, bsp);
}

// Round 12
// 82.436 us; speedup vs baseline: 1.2156x; 1.2156x over previous
//
#include <hip/hip_runtime.h>

#define D        128
#define KCODES   2048
#define NROWS    32768
#define BATCH    8192

typedef _Float16 f16x8 __attribute__((ext_vector_type(8)));
typedef float    f32x4 __attribute__((ext_vector_type(4)));

#define MFMA16(a, b, c) __builtin_amdgcn_mfma_f32_16x16x32_f16((a), (b), (c), 0, 0, 0)
#define INV2048 4.8828125e-4f

static __device__ __forceinline__ void gload16(const void* g, void* l) {
    __builtin_amdgcn_global_load_lds(
        (const __attribute__((address_space(1))) unsigned int*)g,
        (__attribute__((address_space(3))) unsigned int*)l, 16, 0, 0);
}

// ---------------------------------------------------------------------------
// Kernel A: W -> (wh, wl) fp16 hi/lo in 16x16x32 fragment-linear layout +
// fp32 ||W||^2.  For 16-code tile n0, kstep ks, lane l holds
// W[n0*16 + (l&15)][ks*32 + (l>>4)*8 + j], at f16x8 idx ((n0*4+ks)*64+l).
// (verified by absmax 0 in R11)
// ---------------------------------------------------------------------------
__global__ void wconv_kernel(const float* __restrict__ W,
                             _Float16* __restrict__ whf, _Float16* __restrict__ wlf,
                             float* __restrict__ wnorm) {
    int gid = blockIdx.x * 256 + threadIdx.x;    // 32768 = 2048 codes x 16 slots
    int n = gid >> 4, s = gid & 15;
    const float4* src = (const float4*)(W + (size_t)n * D + s * 8);
    float4 a = src[0], b = src[1];
    float va[8] = {a.x, a.y, a.z, a.w, b.x, b.y, b.z, b.w};
    f16x8 hi, lo;
    float ss = 0.0f;
#pragma unroll
    for (int j = 0; j < 8; ++j) {
        _Float16 h = (_Float16)va[j];
        hi[j] = h;
        lo[j] = (_Float16)((va[j] - (float)h) * 2048.0f);
        ss += va[j] * va[j];
    }
    size_t idx = ((size_t)((n >> 4) * 4 + (s >> 2)) * 64 + (s & 3) * 16 + (n & 15));
    ((f16x8*)whf)[idx] = hi;
    ((f16x8*)wlf)[idx] = lo;
#pragma unroll
    for (int m = 1; m <= 8; m <<= 1) ss += __shfl_xor(ss, m);
    if (s == 0) wnorm[n] = ss;
}

// ---------------------------------------------------------------------------
// Kernel B: fused MFMA scores + argmin — rt=4 x ct=2: 24 MFMA per 4 ds_read.
// Grid 512 = 128 row-blocks(256 rows) x 4 code-quarters (XCD-pinned pairs).
// Block 512 thr = 8 waves = 4 wm (64 rows) x 2 p (code-parity halves).
// 8 chunks of 64 codes; 2 x 32KB LDS dbuf + 2KB wnorm = 66KB -> 2 blocks/CU.
// Per chunk per wave: 16 ds_read_b128 + 96 MFMA(16x16x32), 16 acc chains.
// Per-CU cycle ratio MFMA:LDS = 2.4:1 (was 1.2:1 in R11).
// ---------------------------------------------------------------------------
extern "C" __global__ void __launch_bounds__(512)
__attribute__((amdgpu_flat_work_group_size(512, 512)))
__attribute__((amdgpu_waves_per_eu(2, 4)))
vq_argmin(const float* __restrict__ f,
          const _Float16* __restrict__ whf, const _Float16* __restrict__ wlf,
          const float* __restrict__ wnorm,
          float* __restrict__ bsp, int* __restrict__ bcp) {
    extern __shared__ unsigned char lds[];   // [2][32768] dbuf | wnorm @65536

    const int b   = blockIdx.x;
    const int xcd = b & 7;
    const int qrt = xcd >> 1;                 // quarter 0..3 (2 XCDs each)
    const int rb  = (b >> 3) * 2 + (b & 1);   // row block 0..127 (256 rows)
    const int tid = threadIdx.x;
    const int w   = tid >> 6, l = tid & 63;
    const int wm  = w >> 1, p = w & 1;        // 64-row group / code parity
    const int l15 = l & 15, lq = l >> 4;
    const int rowsBase = rb * 256 + wm * 64;

    const char* ghB = (const char*)whf + (size_t)qrt * 131072;
    const char* glB = (const char*)wlf + (size_t)qrt * 131072;

    // chunk c: 64 codes = 16KB hi + 16KB lo
#define STAGE(c) {                                                          \
        unsigned char* dB = lds + ((c) & 1) * 32768;                        \
        gload16(ghB + (size_t)(c) * 16384 + tid * 16,        dB + tid * 16);\
        gload16(ghB + (size_t)(c) * 16384 + 8192 + tid * 16, dB + 8192 + tid * 16);\
        gload16(glB + (size_t)(c) * 16384 + tid * 16,        dB + 16384 + tid * 16);\
        gload16(glB + (size_t)(c) * 16384 + 8192 + tid * 16, dB + 24576 + tid * 16);\
    }

    if (tid < 128)
        gload16((const char*)wnorm + qrt * 2048 + tid * 16, lds + 65536 + tid * 16);
    STAGE(0);

    // ---- A-fragments: 64 rows of (-2*f), hi/lo fp16 (128 VGPR) ----
    f16x8 fh[4][4], fl[4][4];
#pragma unroll
    for (int rt = 0; rt < 4; ++rt) {
#pragma unroll
        for (int ks = 0; ks < 4; ++ks) {
            const float4* pp = (const float4*)(f + (size_t)(rowsBase + rt * 16 + l15) * D
                                               + ks * 32 + lq * 8);
            float4 a = pp[0], bb = pp[1];
            float va[8] = {a.x, a.y, a.z, a.w, bb.x, bb.y, bb.z, bb.w};
            f16x8 hi, lo;
#pragma unroll
            for (int j = 0; j < 8; ++j) {
                float x = -2.0f * va[j];
                _Float16 h = (_Float16)x;
                hi[j] = h;
                lo[j] = (_Float16)((x - (float)h) * 2048.0f);
            }
            fh[rt][ks] = hi;
            fl[rt][ks] = lo;
        }
    }

    __syncthreads();     // chunk 0 + wnorm staged (full vmcnt drain)

    const float* wnL = (const float*)(lds + 65536);

    float bestP[16];
#pragma unroll
    for (int e = 0; e < 16; ++e) bestP[e] = 3.4e38f;

#pragma unroll 1
    for (int t = 0; t < 8; ++t) {
        if (t > 0) {
            asm volatile("s_waitcnt vmcnt(0)" ::: "memory");
            __builtin_amdgcn_s_barrier();
            asm volatile("" ::: "memory");
        }
        if (t < 7) STAGE(t + 1);

        // wave's half of the chunk: 2 tiles of 16 codes at parity p
        const unsigned char* wbh = lds + (t & 1) * 32768 + p * 8192;
        const unsigned char* wbl = wbh + 16384;

        f32x4 accC[4][2], accH[4][2];
#pragma unroll
        for (int rt = 0; rt < 4; ++rt)
#pragma unroll
            for (int ct = 0; ct < 2; ++ct)
#pragma unroll
                for (int r = 0; r < 4; ++r) { accC[rt][ct][r] = 0.0f; accH[rt][ct][r] = 0.0f; }

#pragma unroll
        for (int ks = 0; ks < 4; ++ks) {
            f16x8 wh[2], wl[2];
#pragma unroll
            for (int ct = 0; ct < 2; ++ct) {
                wh[ct] = *(const f16x8*)(wbh + ct * 4096 + ks * 1024 + l * 16);
                wl[ct] = *(const f16x8*)(wbl + ct * 4096 + ks * 1024 + l * 16);
            }
            __builtin_amdgcn_s_setprio(1);
            // 24 MFMAs, 16 chains, same-chain gap 8
#pragma unroll
            for (int ct = 0; ct < 2; ++ct)
#pragma unroll
                for (int rt = 0; rt < 4; ++rt)
                    accC[rt][ct] = MFMA16(fh[rt][ks], wl[ct], accC[rt][ct]);
#pragma unroll
            for (int ct = 0; ct < 2; ++ct)
#pragma unroll
                for (int rt = 0; rt < 4; ++rt)
                    accH[rt][ct] = MFMA16(fh[rt][ks], wh[ct], accH[rt][ct]);
#pragma unroll
            for (int ct = 0; ct < 2; ++ct)
#pragma unroll
                for (int rt = 0; rt < 4; ++rt)
                    accC[rt][ct] = MFMA16(fl[rt][ks], wh[ct], accC[rt][ct]);
            __builtin_amdgcn_s_setprio(0);
        }

        // ---- fold: s = wv + accH + accC/2048; meta = t*2+ct (4 bits) ----
#pragma unroll
        for (int ct = 0; ct < 2; ++ct) {
            const float wv = wnL[t * 64 + p * 32 + ct * 16 + l15];
            const unsigned mv = (unsigned)(t * 2 + ct);
#pragma unroll
            for (int rt = 0; rt < 4; ++rt)
#pragma unroll
                for (int r = 0; r < 4; ++r) {
                    float s = wv + fmaf(accC[rt][ct][r], INV2048, accH[rt][ct][r]);
                    unsigned pk = (__float_as_uint(s) & 0xFFFFFFF0u) | mv;
                    const int e = rt * 4 + r;
                    bestP[e] = fminf(bestP[e], __uint_as_float(pk));
                }
        }
    }
#undef STAGE

    // ---- butterfly over 16 code-cols; parity partials -> LDS merge ----
    __syncthreads();
    float* redS = (float*)lds;                   // [2][256]
    int*   redC = (int*)(lds + 2048);            // [2][256]
#pragma unroll
    for (int e = 0; e < 16; ++e) {
        const int rt = e >> 2, r = e & 3;
        float s = bestP[e];
        unsigned m = __float_as_uint(s) & 15u;
        // code = (qrt*32 + t*4 + p*2 + ct)*16 + col
        int c = qrt * 512 + (int)(m >> 1) * 64 + p * 32 + (int)(m & 1) * 16 + l15;
#pragma unroll
        for (int msk = 1; msk <= 8; msk <<= 1) {
            float s2 = __shfl_xor(s, msk);
            int   c2 = __shfl_xor(c, msk);
            if (s2 < s || (s2 == s && c2 < c)) { s = s2; c = c2; }
        }
        if (l15 == 0) {
            int row = wm * 64 + rt * 16 + lq * 4 + r;    // block-local 0..255
            redS[p * 256 + row] = s;
            redC[p * 256 + row] = c;
        }
    }
    __syncthreads();
    if (tid < 256) {
        float s0 = redS[tid], s1 = redS[256 + tid];
        int   c0 = redC[tid], c1 = redC[256 + tid];
        bool take1 = (s1 < s0) || (s1 == s0 && c1 < c0);
        bsp[(size_t)qrt * NROWS + rb * 256 + tid] = take1 ? s1 : s0;
        bcp[(size_t)qrt * NROWS + rb * 256 + tid] = take1 ? c1 : c0;
    }
}

// ---------------------------------------------------------------------------
// Kernel C: merge the 4 quarter partials, gather W[j], write out + loss.
// ---------------------------------------------------------------------------
__global__ void gather_kernel(const float* __restrict__ f, const float* __restrict__ W,
                              const float* __restrict__ bsp, const int* __restrict__ bcp,
                              float* __restrict__ loss, float* __restrict__ outv) {
    int b  = blockIdx.x;
    int wv = threadIdx.x >> 6;
    int l  = threadIdx.x & 63;
    int n  = b * 4 + wv;
    float s; int c;
    if (l < 4) { s = bsp[(size_t)l * NROWS + n]; c = bcp[(size_t)l * NROWS + n]; }
    else       { s = 3.4e38f; c = 0x7FFFFFFF; }
#pragma unroll
    for (int msk = 1; msk <= 2; msk <<= 1) {
        float s2 = __shfl_xor(s, msk);
        int   c2 = __shfl_xor(c, msk);
        if (s2 < s || (s2 == s && c2 < c)) { s = s2; c = c2; }
    }
    int j = __shfl(c, 0);
    float2 fv = reinterpret_cast<const float2*>(f + (size_t)n * D)[l];
    float2 wj = reinterpret_cast<const float2*>(W + (size_t)j * D)[l];
    reinterpret_cast<float2*>(outv + (size_t)n * D)[l] = wj;
    float dx = fv.x - wj.x, dy = fv.y - wj.y;
    float ls = dx * dx + dy * dy;
#pragma unroll
    for (int off = 32; off; off >>= 1) ls += __shfl_down(ls, off);
    __shared__ float lsm[4];
    if (l == 0) lsm[wv] = ls;
    __syncthreads();
    if (threadIdx.x == 0)
        loss[b] = 1.25f * 0.25f * (lsm[0] + lsm[1] + lsm[2] + lsm[3]);
}

// ---------------------------------------------------------------------------
extern "C" void kernel_launch(void* const* d_in, const int* in_sizes, int n_in,
                              void* d_out, int out_size, void* d_ws, size_t ws_size,
                              hipStream_t stream) {
    const float* f = (const float*)d_in[0];   // [8192,512] -> 32768 rows of 128
    const float* W = (const float*)d_in[1];   // [2048,128]

    float* loss = (float*)d_out;              // [8192]
    float* outv = (float*)d_out + BATCH;      // [8192*512]

    // workspace layout
    float*    wnorm = (float*)d_ws;                              // @0       (8 KB)
    _Float16* whf   = (_Float16*)((char*)d_ws + 8192);           // @8K    (512 KB)
    _Float16* wlf   = (_Float16*)((char*)d_ws + 532480);         // @520K  (512 KB)
    float*    bsp   = (float*)((char*)d_ws + 1056768);           //        (512 KB)
    int*      bcp   = (int*)((char*)d_ws + 1581056);             //        (512 KB)

    wconv_kernel<<<KCODES * 16 / 256, 256, 0, stream>>>(W, whf, wlf, wnorm);

    hipLaunchKernelGGL(vq_argmin, dim3(512), dim3(512), 67584, stream,
                       f, whf, wlf, wnorm, bsp, bcp);

    gather_kernel<<<BATCH, 256, 0, stream>>>(f, W, bsp, bcp, loss, outv);
}

// Round 13
// 78.013 us; speedup vs baseline: 1.2845x; 1.0567x over previous
//
#include <hip/hip_runtime.h>

#define D        128
#define KCODES   2048
#define NROWS    32768
#define BATCH    8192

typedef _Float16 f16x8 __attribute__((ext_vector_type(8)));
typedef float    f32x4 __attribute__((ext_vector_type(4)));

#define MFMA16(a, b, c) __builtin_amdgcn_mfma_f32_16x16x32_f16((a), (b), (c), 0, 0, 0)
#define INV2048 4.8828125e-4f

static __device__ __forceinline__ void gload16(const void* g, void* l) {
    __builtin_amdgcn_global_load_lds(
        (const __attribute__((address_space(1))) unsigned int*)g,
        (__attribute__((address_space(3))) unsigned int*)l, 16, 0, 0);
}

// ---------------------------------------------------------------------------
// Kernel A: W -> (wh, wl) fp16 hi/lo in 16x16x32 fragment-linear layout +
// fp32 ||W||^2.  For 16-code tile n0, kstep ks, lane l holds
// W[n0*16 + (l&15)][ks*32 + (l>>4)*8 + j], at f16x8 idx ((n0*4+ks)*64+l).
// (verified by absmax 0 in R11/R12)
// ---------------------------------------------------------------------------
__global__ void wconv_kernel(const float* __restrict__ W,
                             _Float16* __restrict__ whf, _Float16* __restrict__ wlf,
                             float* __restrict__ wnorm) {
    int gid = blockIdx.x * 256 + threadIdx.x;    // 32768 = 2048 codes x 16 slots
    int n = gid >> 4, s = gid & 15;
    const float4* src = (const float4*)(W + (size_t)n * D + s * 8);
    float4 a = src[0], b = src[1];
    float va[8] = {a.x, a.y, a.z, a.w, b.x, b.y, b.z, b.w};
    f16x8 hi, lo;
    float ss = 0.0f;
#pragma unroll
    for (int j = 0; j < 8; ++j) {
        _Float16 h = (_Float16)va[j];
        hi[j] = h;
        lo[j] = (_Float16)((va[j] - (float)h) * 2048.0f);
        ss += va[j] * va[j];
    }
    size_t idx = ((size_t)((n >> 4) * 4 + (s >> 2)) * 64 + (s & 3) * 16 + (n & 15));
    ((f16x8*)whf)[idx] = hi;
    ((f16x8*)wlf)[idx] = lo;
#pragma unroll
    for (int m = 1; m <= 8; m <<= 1) ss += __shfl_xor(ss, m);
    if (s == 0) wnorm[n] = ss;
}

// ---------------------------------------------------------------------------
// Kernel A2: f -> (-2f) hi/lo fp16 in the SAME fragment-linear layout
// (row tile m0=n>>4, row-in-tile n&15, kstep s>>2, kgroup s&3).
// Paid once; removes the strided-load + convert prologue from vq_argmin
// (which previously redid it 4x chip-wide).
// ---------------------------------------------------------------------------
__global__ void fconv_kernel(const float* __restrict__ f,
                             _Float16* __restrict__ fhf, _Float16* __restrict__ flf) {
    int gid = blockIdx.x * 256 + threadIdx.x;    // 524288 = 32768 rows x 16 slots
    int n = gid >> 4, s = gid & 15;
    const float4* src = (const float4*)(f + (size_t)n * D + s * 8);
    float4 a = src[0], b = src[1];
    float va[8] = {a.x, a.y, a.z, a.w, b.x, b.y, b.z, b.w};
    f16x8 hi, lo;
#pragma unroll
    for (int j = 0; j < 8; ++j) {
        float x = -2.0f * va[j];
        _Float16 h = (_Float16)x;
        hi[j] = h;
        lo[j] = (_Float16)((x - (float)h) * 2048.0f);
    }
    size_t idx = ((size_t)((n >> 4) * 4 + (s >> 2)) * 64 + (s & 3) * 16 + (n & 15));
    ((f16x8*)fhf)[idx] = hi;
    ((f16x8*)flf)[idx] = lo;
}

// ---------------------------------------------------------------------------
// Kernel B: fused MFMA scores + argmin — R11 geometry (measured best), with
// pre-converted A-frags (coalesced dwordx4 loads, no conversion VALU).
// Grid 512 = 128 row-blocks(256 rows) x 4 code-quarters (XCD-pinned pairs).
// Block 512 thr = 8 waves x 32 rows; all waves share the chunk's 64 codes.
// 8 chunks of 64 codes; 2 x 32KB LDS dbuf + 2KB wnorm = 66KB.
// Per chunk per wave: 32 ds_read_b128 + 96 MFMA(16x16x32), 16 acc chains.
// accH inits with wnorm; fold = fmaf + and_or + min.
// ---------------------------------------------------------------------------
extern "C" __global__ void __launch_bounds__(512)
__attribute__((amdgpu_flat_work_group_size(512, 512)))
__attribute__((amdgpu_waves_per_eu(2, 4)))
vq_argmin(const _Float16* __restrict__ fhf, const _Float16* __restrict__ flf,
          const _Float16* __restrict__ whf, const _Float16* __restrict__ wlf,
          const float* __restrict__ wnorm,
          float* __restrict__ bsp, int* __restrict__ bcp) {
    extern __shared__ unsigned char lds[];   // [2][32768] dbuf | wnorm @65536

    const int b   = blockIdx.x;
    const int xcd = b & 7;
    const int qrt = xcd >> 1;                 // quarter 0..3 (2 XCDs each)
    const int rb  = (b >> 3) * 2 + (b & 1);   // row block 0..127 (256 rows)
    const int tid = threadIdx.x;
    const int w   = tid >> 6, l = tid & 63;
    const int l15 = l & 15, lq = l >> 4;
    const int rowsBase = rb * 256 + w * 32;

    const char* ghB = (const char*)whf + (size_t)qrt * 131072;
    const char* glB = (const char*)wlf + (size_t)qrt * 131072;

    // chunk c: 64 codes = 16KB hi + 16KB lo
#define STAGE(c) {                                                          \
        unsigned char* dB = lds + ((c) & 1) * 32768;                        \
        gload16(ghB + (size_t)(c) * 16384 + tid * 16,        dB + tid * 16);\
        gload16(ghB + (size_t)(c) * 16384 + 8192 + tid * 16, dB + 8192 + tid * 16);\
        gload16(glB + (size_t)(c) * 16384 + tid * 16,        dB + 16384 + tid * 16);\
        gload16(glB + (size_t)(c) * 16384 + 8192 + tid * 16, dB + 24576 + tid * 16);\
    }

    if (tid < 128)
        gload16((const char*)wnorm + qrt * 2048 + tid * 16, lds + 65536 + tid * 16);
    STAGE(0);

    // ---- A-fragments: 32 rows, pre-converted, coalesced 16B loads ----
    f16x8 fh[2][4], fl[2][4];
    {
        const f16x8* fhv = (const f16x8*)fhf;
        const f16x8* flv = (const f16x8*)flf;
        const int m0 = rb * 16 + w * 2;       // row tile base (16 rows each)
#pragma unroll
        for (int rt = 0; rt < 2; ++rt)
#pragma unroll
            for (int ks = 0; ks < 4; ++ks) {
                size_t idx = (size_t)((m0 + rt) * 4 + ks) * 64 + l;
                fh[rt][ks] = fhv[idx];
                fl[rt][ks] = flv[idx];
            }
    }

    __syncthreads();     // chunk 0 + wnorm staged (full vmcnt drain)

    const float* wnL = (const float*)(lds + 65536);

    float bestP[8];
#pragma unroll
    for (int e = 0; e < 8; ++e) bestP[e] = 3.4e38f;

#pragma unroll 1
    for (int t = 0; t < 8; ++t) {
        if (t > 0) {
            asm volatile("s_waitcnt vmcnt(0)" ::: "memory");
            __builtin_amdgcn_s_barrier();
            asm volatile("" ::: "memory");
        }
        if (t < 7) STAGE(t + 1);

        const unsigned char* wb = lds + (t & 1) * 32768;

        // accH inits with per-code wnorm (saves the add in the fold)
        float wv[4];
#pragma unroll
        for (int ct = 0; ct < 4; ++ct) wv[ct] = wnL[t * 64 + ct * 16 + l15];

        f32x4 accC[2][4], accH[2][4];
#pragma unroll
        for (int rt = 0; rt < 2; ++rt)
#pragma unroll
            for (int ct = 0; ct < 4; ++ct)
#pragma unroll
                for (int r = 0; r < 4; ++r) { accC[rt][ct][r] = 0.0f; accH[rt][ct][r] = wv[ct]; }

#pragma unroll
        for (int ks = 0; ks < 4; ++ks) {
            f16x8 wh[4], wl[4];
#pragma unroll
            for (int ct = 0; ct < 4; ++ct) {
                wh[ct] = *(const f16x8*)(wb + ((ct * 4 + ks) << 10) + l * 16);
                wl[ct] = *(const f16x8*)(wb + 16384 + ((ct * 4 + ks) << 10) + l * 16);
            }
            __builtin_amdgcn_s_setprio(1);
            // 24 MFMAs, 16 chains, same-chain gap 16
#pragma unroll
            for (int ct = 0; ct < 4; ++ct) {
                accC[0][ct] = MFMA16(fh[0][ks], wl[ct], accC[0][ct]);
                accC[1][ct] = MFMA16(fh[1][ks], wl[ct], accC[1][ct]);
            }
#pragma unroll
            for (int ct = 0; ct < 4; ++ct) {
                accH[0][ct] = MFMA16(fh[0][ks], wh[ct], accH[0][ct]);
                accH[1][ct] = MFMA16(fh[1][ks], wh[ct], accH[1][ct]);
            }
#pragma unroll
            for (int ct = 0; ct < 4; ++ct) {
                accC[0][ct] = MFMA16(fl[0][ks], wh[ct], accC[0][ct]);
                accC[1][ct] = MFMA16(fl[1][ks], wh[ct], accC[1][ct]);
            }
            __builtin_amdgcn_s_setprio(0);
        }

        // ---- fold: s = accH + accC/2048; meta = t*4+ct in low 5 bits ----
#pragma unroll
        for (int ct = 0; ct < 4; ++ct) {
            const unsigned mv = (unsigned)(t * 4 + ct);
#pragma unroll
            for (int rt = 0; rt < 2; ++rt)
#pragma unroll
                for (int r = 0; r < 4; ++r) {
                    float s = fmaf(accC[rt][ct][r], INV2048, accH[rt][ct][r]);
                    unsigned pk = (__float_as_uint(s) & 0xFFFFFFE0u) | mv;
                    const int e = rt * 4 + r;
                    bestP[e] = fminf(bestP[e], __uint_as_float(pk));
                }
        }
    }
#undef STAGE

    // ---- butterfly over 16 code-cols; write quarter partials ----
#pragma unroll
    for (int e = 0; e < 8; ++e) {
        const int rt = e >> 2, r = e & 3;
        float s = bestP[e];
        unsigned m = __float_as_uint(s) & 31u;
        int c = qrt * 512 + (int)(m >> 2) * 64 + (int)(m & 3) * 16 + l15;
#pragma unroll
        for (int msk = 1; msk <= 8; msk <<= 1) {
            float s2 = __shfl_xor(s, msk);
            int   c2 = __shfl_xor(c, msk);
            if (s2 < s || (s2 == s && c2 < c)) { s = s2; c = c2; }
        }
        if (l15 == 0) {
            int row = rowsBase + rt * 16 + lq * 4 + r;
            bsp[(size_t)qrt * NROWS + row] = s;
            bcp[(size_t)qrt * NROWS + row] = c;
        }
    }
}

// ---------------------------------------------------------------------------
// Kernel C: merge the 4 quarter partials, gather W[j], write out + loss.
// ---------------------------------------------------------------------------
__global__ void gather_kernel(const float* __restrict__ f, const float* __restrict__ W,
                              const float* __restrict__ bsp, const int* __restrict__ bcp,
                              float* __restrict__ loss, float* __restrict__ outv) {
    int b  = blockIdx.x;
    int wv = threadIdx.x >> 6;
    int l  = threadIdx.x & 63;
    int n  = b * 4 + wv;
    float s; int c;
    if (l < 4) { s = bsp[(size_t)l * NROWS + n]; c = bcp[(size_t)l * NROWS + n]; }
    else       { s = 3.4e38f; c = 0x7FFFFFFF; }
#pragma unroll
    for (int msk = 1; msk <= 2; msk <<= 1) {
        float s2 = __shfl_xor(s, msk);
        int   c2 = __shfl_xor(c, msk);
        if (s2 < s || (s2 == s && c2 < c)) { s = s2; c = c2; }
    }
    int j = __shfl(c, 0);
    float2 fv = reinterpret_cast<const float2*>(f + (size_t)n * D)[l];
    float2 wj = reinterpret_cast<const float2*>(W + (size_t)j * D)[l];
    reinterpret_cast<float2*>(outv + (size_t)n * D)[l] = wj;
    float dx = fv.x - wj.x, dy = fv.y - wj.y;
    float ls = dx * dx + dy * dy;
#pragma unroll
    for (int off = 32; off; off >>= 1) ls += __shfl_down(ls, off);
    __shared__ float lsm[4];
    if (l == 0) lsm[wv] = ls;
    __syncthreads();
    if (threadIdx.x == 0)
        loss[b] = 1.25f * 0.25f * (lsm[0] + lsm[1] + lsm[2] + lsm[3]);
}

// ---------------------------------------------------------------------------
extern "C" void kernel_launch(void* const* d_in, const int* in_sizes, int n_in,
                              void* d_out, int out_size, void* d_ws, size_t ws_size,
                              hipStream_t stream) {
    const float* f = (const float*)d_in[0];   // [8192,512] -> 32768 rows of 128
    const float* W = (const float*)d_in[1];   // [2048,128]

    float* loss = (float*)d_out;              // [8192]
    float* outv = (float*)d_out + BATCH;      // [8192*512]

    // fh/fl scratch lives in the outv region (16 MB, exact fit); it is fully
    // consumed by vq_argmin before gather_kernel overwrites outv.
    _Float16* fhf = (_Float16*)outv;                              // 8 MB
    _Float16* flf = (_Float16*)((char*)outv + 8388608);           // 8 MB

    // workspace layout
    float*    wnorm = (float*)d_ws;                              // @0       (8 KB)
    _Float16* whf   = (_Float16*)((char*)d_ws + 8192);           // @8K    (512 KB)
    _Float16* wlf   = (_Float16*)((char*)d_ws + 532480);         // @520K  (512 KB)
    float*    bsp   = (float*)((char*)d_ws + 1056768);           //        (512 KB)
    int*      bcp   = (int*)((char*)d_ws + 1581056);             //        (512 KB)

    wconv_kernel<<<KCODES * 16 / 256, 256, 0, stream>>>(W, whf, wlf, wnorm);
    fconv_kernel<<<NROWS * 16 / 256, 256, 0, stream>>>(f, fhf, flf);

    hipLaunchKernelGGL(vq_argmin, dim3(512), dim3(512), 67584, stream,
                       fhf, flf, whf, wlf, wnorm, bsp, bcp);

    gather_kernel<<<BATCH, 256, 0, stream>>>(f, W, bsp, bcp, loss, outv);
}